// Round 11
// baseline (28.014 us; speedup 1.0000x reference)
//
#include <hip/hip_runtime.h>
#include <math.h>

// N=16384, D=64, C=64.
// loss = 1 - (1/n_unique) * sum_c [ (||S_c||^2 - n_c) / (n_c (n_c - 1)) ]
// where S_c = sum of row-normalized feature rows of class c.
//
// 2 graph nodes, NO memset, NO global atomics on the hot path:
//   phase1 (256 blk x 256 thr, ALL CUs): float4 normalize + LDS class
//     accumulate, write block-private partial [blk][64*64] + cntp [blk][64]
//     (fully written every call -> no init, replay-deterministic).
//   finish (16 blk x 256 thr): block k owns classes 4k..4k+3 (256 contiguous
//     columns), coalesced column-reduce over 256 partials, wave-reduce
//     ||S_c||^2; last-arriving block (counter mod 16, valid for any
//     persistent counter value) folds 64 slots -> scalar.

#define NCLS 64
#define DIM 64
#define NB 256
#define THREADS 256
#define ROWS_PER_BLOCK 64             // 16384 / NB
#define FB 16                         // finish blocks

__global__ __launch_bounds__(THREADS) void cpl_phase1(
    const float* __restrict__ feat,   // [n, DIM]
    const int* __restrict__ pred,     // [n]
    float* __restrict__ partial,      // [NB, NCLS*DIM]
    float* __restrict__ cntp,         // [NB, NCLS]
    int n)
{
    __shared__ float s_acc[NCLS * DIM];
    __shared__ float s_cnt[NCLS];
    const int tid = threadIdx.x;

    for (int i = tid; i < NCLS * DIM; i += THREADS) s_acc[i] = 0.0f;
    if (tid < NCLS) s_cnt[tid] = 0.0f;
    __syncthreads();

    const int lane = tid & 63;
    const int wave = tid >> 6;                         // 0..3
    const int rpw  = ROWS_PER_BLOCK / (THREADS / 64);  // 16 rows per wave
    const int row0 = blockIdx.x * ROWS_PER_BLOCK + wave * rpw;
    const int g = lane >> 4;                           // row subgroup 0..3
    const int q = lane & 15;                           // dim quad 0..15

    #pragma unroll
    for (int it = 0; it < rpw / 4; ++it) {             // 4 float4 iterations
        const int rbase = row0 + it * 4;               // wave covers 4 rows
        if (rbase + 3 < n) {
            // lane l -> row rbase+g, dims 4q..4q+3 (one dwordx4, coalesced)
            float4 v = *(const float4*)(feat + (size_t)rbase * DIM + lane * 4);
            float s = v.x * v.x + v.y * v.y + v.z * v.z + v.w * v.w;
            s += __shfl_xor(s, 1, 64);                 // 16-lane group reduce
            s += __shfl_xor(s, 2, 64);
            s += __shfl_xor(s, 4, 64);
            s += __shfl_xor(s, 8, 64);
            float r = rsqrtf(s);
            int c = pred[rbase + g];                   // group-uniform
            float* dst = &s_acc[c * DIM + q * 4];
            atomicAdd(dst + 0, v.x * r);
            atomicAdd(dst + 1, v.y * r);
            atomicAdd(dst + 2, v.z * r);
            atomicAdd(dst + 3, v.w * r);
            if (q == 0) atomicAdd(&s_cnt[c], 1.0f);
        } else {
            for (int r2 = rbase; r2 < rbase + 4 && r2 < n; ++r2) {
                float x = feat[(size_t)r2 * DIM + lane];
                float s = x * x;
                #pragma unroll
                for (int off = 32; off; off >>= 1) s += __shfl_xor(s, off, 64);
                float vv = x * rsqrtf(s);
                int c = pred[r2];
                atomicAdd(&s_acc[c * DIM + lane], vv);
                if (lane == 0) atomicAdd(&s_cnt[c], 1.0f);
            }
        }
    }
    __syncthreads();

    // Block-private partial (float4 stores, 4 per thread). Fully written.
    float4* p4 = (float4*)(partial + (size_t)blockIdx.x * (NCLS * DIM));
    const float4* s4 = (const float4*)s_acc;
    #pragma unroll
    for (int k = 0; k < 4; ++k) p4[tid + k * 256] = s4[tid + k * 256];
    if (tid < NCLS) cntp[blockIdx.x * NCLS + tid] = s_cnt[tid];
}

__global__ __launch_bounds__(256) void cpl_finish(
    const float* __restrict__ partial,  // [NB, NCLS*DIM]
    const float* __restrict__ cntp,     // [NB, NCLS]
    float* __restrict__ slots,          // [FB, 8] (avg,pres per class)
    unsigned* __restrict__ counter,     // [1], NEVER reset (mod-16 trick)
    float* __restrict__ out)            // [1]
{
    __shared__ int s_last;
    const int t = threadIdx.x;
    const int blk = blockIdx.x;         // 0..15
    const int lane = t & 63;
    const int w = t >> 6;               // wave 0..3 -> class blk*4 + w
    const int cls = blk * 4 + w;

    // Column sum: thread owns column (blk*256 + t) of [NB x 4096].
    const int col = blk * 256 + t;
    float s = 0.0f;
    #pragma unroll 8
    for (int b = 0; b < NB; ++b)
        s += partial[(size_t)b * (NCLS * DIM) + col];

    // wave w holds class cls: lane = dim. ||S_c||^2 via wave reduce.
    float sq = s * s;
    sq += __shfl_xor(sq, 1, 64);
    sq += __shfl_xor(sq, 2, 64);
    sq += __shfl_xor(sq, 4, 64);
    sq += __shfl_xor(sq, 8, 64);
    sq += __shfl_xor(sq, 16, 64);
    sq += __shfl_xor(sq, 32, 64);

    // Class count: lane l sums 4 of the 256 cntp entries for cls.
    float c = 0.0f;
    #pragma unroll
    for (int k = 0; k < 4; ++k)
        c += cntp[(lane * 4 + k) * NCLS + cls];
    c += __shfl_xor(c, 1, 64);
    c += __shfl_xor(c, 2, 64);
    c += __shfl_xor(c, 4, 64);
    c += __shfl_xor(c, 8, 64);
    c += __shfl_xor(c, 16, 64);
    c += __shfl_xor(c, 32, 64);

    if (lane == 0) {
        float avg  = (c > 1.5f) ? (sq - c) / (c * (c - 1.0f)) : 0.0f;
        float pres = (c > 0.5f) ? 1.0f : 0.0f;
        __hip_atomic_store(&slots[blk * 8 + w * 2],     avg,
                           __ATOMIC_RELAXED, __HIP_MEMORY_SCOPE_AGENT);
        __hip_atomic_store(&slots[blk * 8 + w * 2 + 1], pres,
                           __ATOMIC_RELAXED, __HIP_MEMORY_SCOPE_AGENT);
    }

    // __syncthreads drains vmcnt; ACQ_REL RMW forms the release/acquire chain.
    __syncthreads();
    if (t == 0) {
        unsigned old = __hip_atomic_fetch_add(counter, 1u, __ATOMIC_ACQ_REL,
                                              __HIP_MEMORY_SCOPE_AGENT);
        s_last = ((old & (FB - 1)) == FB - 1);   // fires once per FB bumps
    }
    __syncthreads();
    if (!s_last) return;

    // Last block: 64 avg entries at even slots, 64 pres at odd.
    if (t < 64) {
        float a  = __hip_atomic_load(&slots[2 * t],     __ATOMIC_RELAXED,
                                     __HIP_MEMORY_SCOPE_AGENT);
        float pr = __hip_atomic_load(&slots[2 * t + 1], __ATOMIC_RELAXED,
                                     __HIP_MEMORY_SCOPE_AGENT);
        #pragma unroll
        for (int off = 32; off; off >>= 1) {
            a  += __shfl_xor(a, off, 64);
            pr += __shfl_xor(pr, off, 64);
        }
        if (t == 0) out[0] = 1.0f - a / pr;
    }
}

extern "C" void kernel_launch(void* const* d_in, const int* in_sizes, int n_in,
                              void* d_out, int out_size, void* d_ws, size_t ws_size,
                              hipStream_t stream) {
    const float* feat = (const float*)d_in[0];
    const int*   pred = (const int*)d_in[1];
    float* out = (float*)d_out;
    const int n = in_sizes[1];                 // 16384

    float*    partial = (float*)d_ws;                          // NB*4096
    float*    cntp    = partial + (size_t)NB * (NCLS * DIM);   // NB*64
    float*    slots   = cntp + NB * NCLS;                      // FB*8
    unsigned* counter = (unsigned*)(slots + FB * 8);           // 1, never reset

    cpl_phase1<<<NB, THREADS, 0, stream>>>(feat, pred, partial, cntp, n);
    cpl_finish<<<FB, 256, 0, stream>>>(partial, cntp, slots, counter, out);
}